// Round 21
// baseline (67.841 us; speedup 1.0000x reference)
//
#include <hip/hip_runtime.h>
#include <stdint.h>

// Problem: B,T,C = 2,768,64; N_HEAD=64 -> head_dim=1; fp32 buffers.
// R20 FAILED: comb builder kept R19's "two groups of MB/2" pattern after MB
// shrank 32->24 -> groups of 24: comb[12..23] got future-suffix of PM/PMv
// (wrong semantics) and threads 24..47 wrote OOB past comb[24]. R21 fixes:
// 24 threads, two groups of 12 (future FM/FMv at +0..11, past PM/PMv at
// +12..23). Everything else identical to R20 (degree-5 moments, geometric
// past weights, R17-validated skeleton).
constexpr int Tc = 768;
constexpr int Hc = 64;
constexpr int Bc = 2;
constexpr int NT = 12;                 // 64-wide j-blocks per sequence
constexpr int NM = 6;                  // moments 0..5 (Taylor degree 5)
constexpr int MB = 4 * NM;             // 24 floats per block table
constexpr float LOG2E = 1.44269504088896f;
constexpr float LN2   = 0.69314718056f;
constexpr size_t SLAB = (size_t)Bc * Hc * Tc;        // 98304 floats

typedef float v2f __attribute__((ext_vector_type(2)));
typedef float v4f __attribute__((ext_vector_type(4)));

// ---------------------------------------------------------------------------
// Kernel A: projection + per-block degree-5 moments.
// grid (24, 64) x 64 thr = 1536 single-wave blocks = 6 waves/CU.
//   MOM[bh][B][0..5]=sum k^m, [6..11]=sum k^m v,
//            [12..17]=sum k^m 2^{s(j-eB)}, [18..23]=... * v   (eB=B*64+63)
// ---------------------------------------------------------------------------
__global__ __launch_bounds__(64) void proj_mom_kernel(
    const float* __restrict__ x, const float* __restrict__ W,
    const float* __restrict__ vtmp, const float* __restrict__ ptmp,
    float* __restrict__ qs, float* __restrict__ ks, float* __restrict__ vs,
    float* __restrict__ MOM)
{
    const int lane = threadIdx.x & 63;
    const int bx   = blockIdx.x;                 // 0..23 = b*12 + B
    const int b    = bx / NT;
    const int B    = bx - b * NT;
    const int t    = B * 64 + lane;
    const int g    = bx * 64 + lane;             // row in x (b*768 + t)
    const int h    = blockIdx.y;                 // block-uniform
    const int bh   = b * Hc + h;

    const v4f* xp = (const v4f*)(x + (size_t)g * 64);
    const float* __restrict__ wq = W + h * 64;
    const float* __restrict__ wk = W + (64 + h) * 64;
    float aq = 0.f, ak = 0.f;
#pragma unroll
    for (int c = 0; c < 16; ++c) {
        v4f u = xp[c];
        aq = fmaf(u.x, wq[4*c],   aq);  ak = fmaf(u.x, wk[4*c],   ak);
        aq = fmaf(u.y, wq[4*c+1], aq);  ak = fmaf(u.y, wk[4*c+1], ak);
        aq = fmaf(u.z, wq[4*c+2], aq);  ak = fmaf(u.z, wk[4*c+2], ak);
        aq = fmaf(u.w, wq[4*c+3], aq);  ak = fmaf(u.w, wk[4*c+3], ak);
    }
    const float vv = x[(size_t)g * 64 + h] * vtmp[h] * ptmp[h];
    const size_t o = (size_t)bh * Tc + t;        // lane-coalesced
    qs[o] = aq * LOG2E;
    ks[o] = ak;
    vs[o] = vv;

    const float slope2 = exp2f(-0.125f * (float)(h + 1)) * LOG2E;
    const float lf = exp2f(slope2 * (float)(lane - 63));   // 2^{s(j-eB)} <= 1

    float km[NM];
    km[0] = 1.f;
#pragma unroll
    for (int m = 1; m < NM; ++m) km[m] = km[m - 1] * ak;

    float r[MB];
#pragma unroll
    for (int m = 0; m < NM; ++m) {
        const float kl2 = km[m] * lf;
        r[m]           = km[m];
        r[NM + m]      = km[m] * vv;
        r[2 * NM + m]  = kl2;
        r[3 * NM + m]  = kl2 * vv;
    }
#define DPP_PASS(CTRL)                                                        \
    _Pragma("unroll")                                                         \
    for (int ii = 0; ii < MB; ++ii)                                           \
        r[ii] += __int_as_float(__builtin_amdgcn_update_dpp(                  \
            0, __float_as_int(r[ii]), CTRL, 0xf, 0xf, true));
    DPP_PASS(0x111)
    DPP_PASS(0x112)
    DPP_PASS(0x114)
    DPP_PASS(0x118)
    DPP_PASS(0x142)
    DPP_PASS(0x143)
#undef DPP_PASS

    if (lane == 63) {
        float* mp = MOM + ((size_t)bh * NT + B) * MB;
#pragma unroll
        for (int m = 0; m < MB / 4; ++m) {
            v4f s4 = { r[4*m], r[4*m+1], r[4*m+2], r[4*m+3] };
            *(v4f*)(mp + 4 * m) = s4;
        }
    }
}

// ---------------------------------------------------------------------------
// Kernel B: attention, suffix/prefix-collapsed degree-5 moments.
// grid (12,64,2) x 256 = 6 blocks/CU. Block = 64-row tile rt of (b,h).
//  stage: MOM[bh] (288 f) + diag k/v (128 f) -> LDS.
//  comb[24] by 24 threads, groups of 12 (FIX vs R20):
//   comb[0..11]  = sum_{B>rt} FM/FMv[m]            (momL offsets +0..11)
//   comb[12..23] = sum_{B<rt} wgt_B * PM/PMv[m]    (momL offsets +12..23),
//   geometric weights downward: wgt = 2^{-s} at B=rt-1, *= 2^{-64s}/step.
//  per row: wave0 adds off-diag (2 six-term evals + row factor 2^{s(r0-i)});
//  every wave computes its validated 16-j diagonal quarter (exact exp2).
// ---------------------------------------------------------------------------
__global__ __launch_bounds__(256, 6) void attn_kernel(
    const float* __restrict__ qs, const float* __restrict__ ks,
    const float* __restrict__ vs, const float* __restrict__ MOM,
    float* __restrict__ out)
{
    const int tid  = threadIdx.x;
    const int lane = tid & 63;
    const int w    = __builtin_amdgcn_readfirstlane(tid >> 6);
    const int rt   = blockIdx.x;     // 0..11
    const int h    = blockIdx.y;
    const int b    = blockIdx.z;
    const int bh   = b * Hc + h;

    __shared__ float momL[NT * MB];              // 288 floats
    __shared__ float kd[64], vd[64];
    __shared__ float comb[MB];
    __shared__ float psum[4][64], pacc[4][64];

    // ---- stage: moments (96x3) + diag k/v ----
    {
        const float* __restrict__ mbp = MOM + (size_t)bh * (NT * MB);
        if (tid < 96) {
            momL[tid]       = mbp[tid];
            momL[tid + 96]  = mbp[tid + 96];
            momL[tid + 192] = mbp[tid + 192];
        } else if (tid < 160) {
            kd[tid - 96] = ks[(size_t)bh * Tc + rt * 64 + (tid - 96)];
        } else if (tid < 224) {
            vd[tid - 160] = vs[(size_t)bh * Tc + rt * 64 + (tid - 160)];
        }
    }
    const float slope2 = exp2f(-0.125f * (float)(h + 1)) * LOG2E;
    __syncthreads();

    // ---- collapse blocks: 24 threads, groups of 12 (FIXED) ----
    if (tid < MB) {
        const int grp = tid >= 2 * NM;   // 0 = future suffix, 1 = past prefix
        const int m   = tid - (grp ? 2 * NM : 0);    // 0..11 within group
        float acc = 0.f;
        if (!grp) {
            for (int B = rt + 1; B < NT; ++B)
                acc += momL[B * MB + m];                  // FM/FMv
        } else {
            // geometric weights, downward for clean underflow (no 0*inf)
            float wgt = exp2f(-slope2);                   // B = rt-1
            const float ratio = exp2f(-64.f * slope2);
            for (int B = rt - 1; B >= 0; --B) {
                acc = fmaf(wgt, momL[B * MB + 2 * NM + m], acc);   // PM/PMv
                wgt *= ratio;                             // -> exact 0 far past
            }
        }
        comb[tid] = acc;
    }
    __syncthreads();

    // ---- per-row state ----
    const int i = rt * 64 + lane;
    const float q2 = qs[(size_t)bh * Tc + i];    // q * log2e (coalesced)
    const float fi2 = slope2 * (float)i;

    // Taylor p_m = q^m/m!  (q natural = q2*ln2), degree 5
    const float z  = q2 * LN2;
    const float p1 = z;
    const float p2 = z * p1 * 0.5f;
    const float p3 = z * p2 * (1.f / 3.f);
    const float p4 = z * p3 * 0.25f;
    const float p5 = z * p4 * 0.2f;

    float S = 0.f, A = 0.f;
    if (w == 0) {
        float sf = comb[0];
        sf = fmaf(p1, comb[1], sf); sf = fmaf(p2, comb[2], sf);
        sf = fmaf(p3, comb[3], sf); sf = fmaf(p4, comb[4], sf);
        sf = fmaf(p5, comb[5], sf);
        float af = comb[6];
        af = fmaf(p1, comb[7],  af); af = fmaf(p2, comb[8],  af);
        af = fmaf(p3, comb[9],  af); af = fmaf(p4, comb[10], af);
        af = fmaf(p5, comb[11], af);
        float sp = comb[12];
        sp = fmaf(p1, comb[13], sp); sp = fmaf(p2, comb[14], sp);
        sp = fmaf(p3, comb[15], sp); sp = fmaf(p4, comb[16], sp);
        sp = fmaf(p5, comb[17], sp);
        float ap = comb[18];
        ap = fmaf(p1, comb[19], ap); ap = fmaf(p2, comb[20], ap);
        ap = fmaf(p3, comb[21], ap); ap = fmaf(p4, comb[22], ap);
        ap = fmaf(p5, comb[23], ap);
        const float f = __builtin_amdgcn_exp2f(-slope2 * (float)lane); // 2^{s(r0-i)}
        S = fmaf(f, sp, sf);
        A = fmaf(f, ap, af);
    }

    // ---- diagonal slice (validated R17-R19): wave w -> j in [r0+16w,+16) ----
    v2f cu2[8];
#pragma unroll
    for (int u = 0; u < 8; ++u) {
        cu2[u].x = slope2 * (float)(2 * u);
        cu2[u].y = slope2 * (float)(2 * u + 1);
    }
    const float mb = slope2 * (float)(rt * 64 + 16 * w) - fi2;  // s*(jw - i)
    const v2f mb2 = {mb, mb};
    const v2f q2v = {q2, q2};
    v2f sum2 = {0.f, 0.f}, acc2 = {0.f, 0.f};
    const v2f* __restrict__ k2p = (const v2f*)kd;
    const v2f* __restrict__ v2p = (const v2f*)vd;
#pragma unroll
    for (int u = 0; u < 8; ++u) {
        v2f k2 = k2p[8 * w + u];                 // ds_read_b64 broadcast
        v2f v2 = v2p[8 * w + u];
        v2f t2 = mb2 + cu2[u];
        v2f bias;
        bias.x = fminf(t2.x, 0.f);
        bias.y = fminf(t2.y, 0.f);
        v2f sc = q2v * k2 + bias;
        v2f e;
        e.x = __builtin_amdgcn_exp2f(sc.x);
        e.y = __builtin_amdgcn_exp2f(sc.y);
        sum2 += e;
        acc2 = e * v2 + acc2;
    }
    S += sum2.x + sum2.y;
    A += acc2.x + acc2.y;

    psum[w][lane] = S;
    pacc[w][lane] = A;
    __syncthreads();

    if (tid < 64) {
        float s = psum[0][lane] + psum[1][lane] + psum[2][lane] + psum[3][lane];
        float a = pacc[0][lane] + pacc[1][lane] + pacc[2][lane] + pacc[3][lane];
        out[((size_t)(b * Tc + rt * 64 + lane)) * 64 + h] =
            a * __builtin_amdgcn_rcpf(s);
    }
}

extern "C" void kernel_launch(void* const* d_in, const int* in_sizes, int n_in,
                              void* d_out, int out_size, void* d_ws, size_t ws_size,
                              hipStream_t stream) {
    const float* x    = (const float*)d_in[0];
    const float* W    = (const float*)d_in[1];
    const float* vtmp = (const float*)d_in[2];
    const float* ptmp = (const float*)d_in[3];
    float* out = (float*)d_out;

    float* qsl = (float*)d_ws;
    float* ksl = qsl + SLAB;
    float* vsl = ksl + SLAB;
    float* mom = vsl + SLAB;           // [bh][12][24]

    proj_mom_kernel<<<dim3(24, Hc), 64, 0, stream>>>(
        x, W, vtmp, ptmp, qsl, ksl, vsl, mom);
    attn_kernel<<<dim3(NT, Hc, Bc), 256, 0, stream>>>(
        qsl, ksl, vsl, mom, out);
}